// Round 7
// baseline (1384.060 us; speedup 1.0000x reference)
//
#include <hip/hip_runtime.h>

#define N_USERS 100000
#define N_ITEMS 50000
#define N_NODES 150000
#define DIM     32
#define N_EDGES 2400000
#define K_STEPS 10

#define SCAN_CHUNK 1024
#define NB_SCAN ((N_NODES + SCAN_CHUNK - 1) / SCAN_CHUNK)   // 147 blocks
#define WDEQ 3.814697265625e-06f   // 2^-18

#define CH   4096      // edges per sscatter workgroup
#define NSB  147       // src buckets: psrc >> 10
#define NSBP 160       // padded

typedef float v2f __attribute__((ext_vector_type(2)));

// ---------------- helpers: bf16 / fp8 ----------------
__device__ __forceinline__ float bflo(unsigned u) { return __uint_as_float(u << 16); }
__device__ __forceinline__ float bfhi(unsigned u) { return __uint_as_float(u & 0xffff0000u); }
__device__ __forceinline__ unsigned packbf(float a, float b) {   // RNE pack
    unsigned ua = __float_as_uint(a), ub = __float_as_uint(b);
    ua += 0x7fffu + ((ua >> 16) & 1u);
    ub += 0x7fffu + ((ub >> 16) & 1u);
    return (ua >> 16) | (ub & 0xffff0000u);
}
__device__ __forceinline__ unsigned pack_fp8x4(float a, float b, float c, float d) {
    unsigned r = 0;
    r = __builtin_amdgcn_cvt_pk_fp8_f32(a, b, r, false);   // bytes 0,1
    r = __builtin_amdgcn_cvt_pk_fp8_f32(c, d, r, true);    // bytes 2,3
    return r;
}
#define UNPACK_FP8X4(d, f0, f1, f2, f3)                          \
    { v2f _lo = __builtin_amdgcn_cvt_pk_f32_fp8((d), false);     \
      v2f _hi = __builtin_amdgcn_cvt_pk_f32_fp8((d), true);      \
      f0 = _lo[0]; f1 = _lo[1]; f2 = _hi[0]; f3 = _hi[1]; }

// ---------------- norm reduction: max over rows of sum(x^2) ----------------
__global__ void norm_kernel(const float* __restrict__ xu, const float* __restrict__ xi,
                            unsigned int* __restrict__ norm_bits) {
    int gid = blockIdx.x * blockDim.x + threadIdx.x;
    int row = gid >> 3;
    int q   = gid & 7;
    float s = 0.0f;
    if (row < N_NODES) {
        const float* x = (row < N_USERS) ? (xu + (size_t)row * DIM)
                                         : (xi + (size_t)(row - N_USERS) * DIM);
        float4 v = *(const float4*)(x + q * 4);
        s = v.x * v.x + v.y * v.y + v.z * v.z + v.w * v.w;
    }
    s += __shfl_xor(s, 1);
    s += __shfl_xor(s, 2);
    s += __shfl_xor(s, 4);
    s = fmaxf(s, __shfl_xor(s, 8));
    s = fmaxf(s, __shfl_xor(s, 16));
    s = fmaxf(s, __shfl_xor(s, 32));
    __shared__ float smax[4];
    int wave = threadIdx.x >> 6;
    if ((threadIdx.x & 63) == 0) smax[wave] = s;
    __syncthreads();
    if (threadIdx.x == 0) {
        float m = fmaxf(fmaxf(smax[0], smax[1]), fmaxf(smax[2], smax[3]));
        atomicMax(norm_bits, __float_as_uint(m));   // non-neg: uint order == float order
    }
}

// --------------------------- degree histogram ------------------------------
__global__ void hist_kernel(const int* __restrict__ ed, int* __restrict__ deg) {
    int e = blockIdx.x * blockDim.x + threadIdx.x;
    if (e >= N_EDGES) return;
    atomicAdd(&deg[ed[e]], 1);
}

// ----------------- degree-bucket counts (64 buckets) -----------------------
__global__ void degcnt_kernel(const int* __restrict__ deg, int* __restrict__ cnt) {
    __shared__ int lc[64];
    if (threadIdx.x < 64) lc[threadIdx.x] = 0;
    __syncthreads();
    int d = blockIdx.x * blockDim.x + threadIdx.x;
    if (d < N_NODES) {
        int dg = deg[d];
        atomicAdd(&lc[dg > 63 ? 63 : dg], 1);
    }
    __syncthreads();
    if (threadIdx.x < 64 && lc[threadIdx.x]) atomicAdd(&cnt[threadIdx.x], lc[threadIdx.x]);
}

// ------------- exclusive scan of the 64 bucket counts (1 wave) -------------
__global__ void scan_cnt_kernel(int* __restrict__ cnt) {
    int tid = threadIdx.x;          // 64 threads = 1 wave
    int v = cnt[tid];
    int inc = v;
    for (int off = 1; off < 64; off <<= 1) {
        int t = __shfl_up(inc, off);
        if (tid >= off) inc += t;
    }
    cnt[tid] = inc - v;             // exclusive offset; ticket advances it
}

// --- ticket: degree-sorted permutation. perm[pos]=node, pindex[node]=pos ---
__global__ void ticket_kernel(const int* __restrict__ deg, int* __restrict__ cnt,
                              int* __restrict__ perm, int* __restrict__ pindex,
                              int* __restrict__ pdeg, float* __restrict__ alphap,
                              const float* __restrict__ alpha_logit) {
    __shared__ int lcnt[64];
    __shared__ int lbase[64];
    int tid = threadIdx.x;
    if (tid < 64) lcnt[tid] = 0;
    __syncthreads();
    int d = blockIdx.x * blockDim.x + tid;
    int b = 0, rank = 0, dg = 0;
    if (d < N_NODES) {
        dg = deg[d];
        b = dg > 63 ? 63 : dg;
        rank = atomicAdd(&lcnt[b], 1);
    }
    __syncthreads();
    if (tid < 64 && lcnt[tid]) lbase[tid] = atomicAdd(&cnt[tid], lcnt[tid]);
    __syncthreads();
    if (d < N_NODES) {
        int pos = lbase[b] + rank;
        perm[pos] = d;
        pindex[d] = pos;
        pdeg[pos] = dg;
        alphap[pos] = 1.0f / (1.0f + __expf(-alpha_logit[d]));
    }
}

// ------------- per-block exclusive scan over pdeg (1024/block) -------------
__global__ void scan_block_kernel(const int* __restrict__ pdeg, int* __restrict__ excl,
                                  int* __restrict__ blockSums) {
    int base = blockIdx.x * SCAN_CHUNK + threadIdx.x * 4;
    int v0 = 0, v1 = 0, v2 = 0, v3 = 0;
    if (base + 3 < N_NODES) {
        int4 t = *(const int4*)(pdeg + base);
        v0 = t.x; v1 = t.y; v2 = t.z; v3 = t.w;
    } else {
        if (base + 0 < N_NODES) v0 = pdeg[base + 0];
        if (base + 1 < N_NODES) v1 = pdeg[base + 1];
        if (base + 2 < N_NODES) v2 = pdeg[base + 2];
    }
    int s = v0 + v1 + v2 + v3;
    int lane = threadIdx.x & 63;
    int inc = s;
    for (int off = 1; off < 64; off <<= 1) {
        int t = __shfl_up(inc, off);
        if (lane >= off) inc += t;
    }
    __shared__ int wsum[4];
    int wave = threadIdx.x >> 6;
    if (lane == 63) wsum[wave] = inc;
    __syncthreads();
    int woff = 0;
    for (int w = 0; w < 4; ++w) if (w < wave) woff += wsum[w];
    int excl_thread = woff + inc - s;
    if (base + 0 < N_NODES) excl[base + 0] = excl_thread;
    if (base + 1 < N_NODES) excl[base + 1] = excl_thread + v0;
    if (base + 2 < N_NODES) excl[base + 2] = excl_thread + v0 + v1;
    if (base + 3 < N_NODES) excl[base + 3] = excl_thread + v0 + v1 + v2;
    if (threadIdx.x == 255) blockSums[blockIdx.x] = woff + inc;
}

__global__ void scan_sums_kernel(int* __restrict__ blockSums) {
    __shared__ int buf[256];
    int tid = threadIdx.x;
    int v = (tid < NB_SCAN) ? blockSums[tid] : 0;
    buf[tid] = v;
    __syncthreads();
    for (int off = 1; off < 256; off <<= 1) {
        int t = (tid >= off) ? buf[tid - off] : 0;
        __syncthreads();
        buf[tid] += t;
        __syncthreads();
    }
    if (tid < NB_SCAN) blockSums[tid] = buf[tid] - v;   // exclusive
}

// prow[i] += blockoffset; sentinel prow[N_NODES] = N_EDGES
__global__ void add_offsets_kernel(int* __restrict__ prow, const int* __restrict__ blockSums) {
    int i = blockIdx.x * blockDim.x + threadIdx.x;
    if (i == 0) prow[N_NODES] = N_EDGES;
    if (i >= N_NODES) return;
    prow[i] += blockSums[i >> 10];
}

// pcursor[i] = prow[i]  (fill cursors in permuted-row space)
__global__ void pcopy_kernel(const int* __restrict__ prow, int* __restrict__ pcursor) {
    int i = blockIdx.x * blockDim.x + threadIdx.x;
    if (i < N_NODES) pcursor[i] = prow[i];
}

// ----------- src-bucket histogram over psrc>>10 (147 buckets) --------------
__global__ void sbh_kernel(const int* __restrict__ es, const int* __restrict__ pindex,
                           int* __restrict__ sbh) {
    __shared__ int lc[NSBP];
    if (threadIdx.x < NSBP) lc[threadIdx.x] = 0;
    __syncthreads();
    int e = blockIdx.x * blockDim.x + threadIdx.x;
    if (e < N_EDGES) atomicAdd(&lc[pindex[es[e]] >> 10], 1);
    __syncthreads();
    if (threadIdx.x < NSBP && lc[threadIdx.x]) atomicAdd(&sbh[threadIdx.x], lc[threadIdx.x]);
}

// -------- exclusive scan of src-bucket counts, in place (1 block) ----------
__global__ void sscan_kernel(int* __restrict__ sbh) {
    __shared__ int buf[256];
    int tid = threadIdx.x;
    int v = (tid < NSBP) ? sbh[tid] : 0;
    buf[tid] = v;
    __syncthreads();
    for (int off = 1; off < 256; off <<= 1) {
        int t = (tid >= off) ? buf[tid - off] : 0;
        __syncthreads();
        buf[tid] += t;
        __syncthreads();
    }
    if (tid < NSBP) sbh[tid] = buf[tid] - v;   // becomes global bucket cursor
}

// --- LDS-staged coalesced scatter: edges -> E1, bucketed by psrc>>10 -------
// E1[k] = { csrword = pindex[src]<<14 | q14,  row = pindex[dst] }
__global__ __launch_bounds__(256) void sscatter_kernel(
        const int* __restrict__ es, const int* __restrict__ ed,
        const float* __restrict__ ew, const int* __restrict__ pindex,
        int* __restrict__ sbh, uint2* __restrict__ E1) {
    __shared__ int hist[NSBP];
    __shared__ int start[NSBP];
    __shared__ int lcur[NSBP];
    __shared__ int gbase[NSBP];
    __shared__ uint2 stage[CH];
    __shared__ unsigned char sbkt[CH];
    __shared__ int buf[256];
    int tid = threadIdx.x;
    int base0 = blockIdx.x * CH;
    int count = N_EDGES - base0;
    if (count > CH) count = CH;
    if (tid < NSBP) hist[tid] = 0;
    __syncthreads();
    // pass 1: local histogram
    for (int k = tid; k < count; k += 256)
        atomicAdd(&hist[pindex[es[base0 + k]] >> 10], 1);
    __syncthreads();
    // exclusive scan of hist -> start, lcur
    int v = (tid < NSBP) ? hist[tid] : 0;
    buf[tid] = v;
    __syncthreads();
    for (int off = 1; off < 256; off <<= 1) {
        int t = (tid >= off) ? buf[tid - off] : 0;
        __syncthreads();
        buf[tid] += t;
        __syncthreads();
    }
    if (tid < NSBP) { start[tid] = buf[tid] - v; lcur[tid] = buf[tid] - v; }
    __syncthreads();
    // pass 2: stage payloads grouped by bucket
    for (int k = tid; k < count; k += 256) {
        int e = base0 + k;
        int ps = pindex[es[e]];
        int b  = ps >> 10;
        float w = ew[e];
        unsigned q = (unsigned)(w * 262144.0f + 0.5f);
        if (q > 16383u) q = 16383u;
        uint2 p;
        p.x = ((unsigned)ps << 14) | q;
        p.y = (unsigned)pindex[ed[e]];
        int lp = atomicAdd(&lcur[b], 1);
        stage[lp] = p;
        sbkt[lp] = (unsigned char)b;
    }
    __syncthreads();
    // pass 3: reserve global space per bucket
    if (tid < NSBP) gbase[tid] = hist[tid] ? atomicAdd(&sbh[tid], hist[tid]) : 0;
    __syncthreads();
    // pass 4: coalesced write-out (consecutive slots of a bucket -> consecutive global)
    for (int k = tid; k < count; k += 256) {
        int b = sbkt[k];
        E1[gbase[b] + (k - start[b])] = stage[k];
    }
}

// ---- fill from src-sorted stream: rows get entries in ~ascending psrc -----
__global__ void fill2_kernel(const uint2* __restrict__ E1,
                             int* __restrict__ pcursor, unsigned* __restrict__ csr) {
    int e = blockIdx.x * blockDim.x + threadIdx.x;
    if (e >= N_EDGES) return;
    uint2 p = E1[e];
    int pos = atomicAdd(&pcursor[p.y], 1);
    csr[pos] = p.x;
}

// --- init: h(d_out) = x/norm; permuted fp8 mirror h8p; bf16 st16p ----------
__global__ void init_kernel(const float* __restrict__ xu, const float* __restrict__ xi,
                            const float* __restrict__ su, const float* __restrict__ si,
                            const unsigned int* __restrict__ norm_bits,
                            const int* __restrict__ pindex,
                            float* __restrict__ h, unsigned* __restrict__ h8p,
                            unsigned* __restrict__ st16p) {
    int gid = blockIdx.x * blockDim.x + threadIdx.x;
    int d = gid >> 3;
    int q = gid & 7;
    if (d >= N_NODES) return;
    float rn = rsqrtf(__uint_as_float(*norm_bits));
    int fbase = d * DIM + (q << 2);
    const float* x = (d < N_USERS) ? (xu + fbase) : (xi + fbase - N_USERS * DIM);
    const float* s = (d < N_USERS) ? (su + fbase) : (si + fbase - N_USERS * DIM);
    float4 v = *(const float4*)x;
    v.x *= rn; v.y *= rn; v.z *= rn; v.w *= rn;
    *(float4*)(h + fbase) = v;
    int i = pindex[d];
    h8p[(i << 3) + q] = pack_fp8x4(v.x, v.y, v.z, v.w);
    float4 sv = *(const float4*)s;
    uint2 sp;
    sp.x = packbf(sv.x * rn, sv.y * rn);
    sp.y = packbf(sv.z * rn, sv.w * rn);
    *(uint2*)(st16p + (i << 4) + (q << 1)) = sp;
}

// ---- hop-1 gather: t8p[i] = fp8( sum w * fp8row(h8p[psrc]) ) --------------
// 8 lanes/node, 1 dword (4 fp8) per lane per edge, unroll 4.
__global__ void gather1_kernel(const unsigned* __restrict__ h8p,
                               unsigned* __restrict__ t8p,
                               const unsigned* __restrict__ csr,
                               const int* __restrict__ prow) {
    int gid = blockIdx.x * blockDim.x + threadIdx.x;
    int i = gid >> 3;
    int q = gid & 7;
    if (i >= N_NODES) return;
    int j   = prow[i];
    int end = prow[i + 1];
    float a0 = 0, a1 = 0, a2 = 0, a3 = 0;
    for (; j + 4 <= end; j += 4) {
        unsigned e0 = __builtin_nontemporal_load(csr + j);
        unsigned e1 = __builtin_nontemporal_load(csr + j + 1);
        unsigned e2 = __builtin_nontemporal_load(csr + j + 2);
        unsigned e3 = __builtin_nontemporal_load(csr + j + 3);
        float w0 = (float)(e0 & 0x3fffu) * WDEQ;
        float w1 = (float)(e1 & 0x3fffu) * WDEQ;
        float w2 = (float)(e2 & 0x3fffu) * WDEQ;
        float w3 = (float)(e3 & 0x3fffu) * WDEQ;
        unsigned d0 = h8p[((e0 >> 14) << 3) + q];
        unsigned d1 = h8p[((e1 >> 14) << 3) + q];
        unsigned d2 = h8p[((e2 >> 14) << 3) + q];
        unsigned d3 = h8p[((e3 >> 14) << 3) + q];
        float f0, f1, f2, f3;
        UNPACK_FP8X4(d0, f0, f1, f2, f3);
        a0 = fmaf(w0, f0, a0); a1 = fmaf(w0, f1, a1);
        a2 = fmaf(w0, f2, a2); a3 = fmaf(w0, f3, a3);
        UNPACK_FP8X4(d1, f0, f1, f2, f3);
        a0 = fmaf(w1, f0, a0); a1 = fmaf(w1, f1, a1);
        a2 = fmaf(w1, f2, a2); a3 = fmaf(w1, f3, a3);
        UNPACK_FP8X4(d2, f0, f1, f2, f3);
        a0 = fmaf(w2, f0, a0); a1 = fmaf(w2, f1, a1);
        a2 = fmaf(w2, f2, a2); a3 = fmaf(w2, f3, a3);
        UNPACK_FP8X4(d3, f0, f1, f2, f3);
        a0 = fmaf(w3, f0, a0); a1 = fmaf(w3, f1, a1);
        a2 = fmaf(w3, f2, a2); a3 = fmaf(w3, f3, a3);
    }
    for (; j < end; ++j) {
        unsigned e0 = __builtin_nontemporal_load(csr + j);
        float w0 = (float)(e0 & 0x3fffu) * WDEQ;
        unsigned d0 = h8p[((e0 >> 14) << 3) + q];
        float f0, f1, f2, f3;
        UNPACK_FP8X4(d0, f0, f1, f2, f3);
        a0 = fmaf(w0, f0, a0); a1 = fmaf(w0, f1, a1);
        a2 = fmaf(w0, f2, a2); a3 = fmaf(w0, f3, a3);
    }
    t8p[(i << 3) + q] = pack_fp8x4(a0, a1, a2, a3);
}

// ---- hop-2 gather + update; h stays fp32 node-indexed in d_out ------------
__global__ void gather2_update_kernel(const unsigned* __restrict__ t8p,
                                      float* __restrict__ h,
                                      unsigned* __restrict__ h8p,
                                      const unsigned* __restrict__ csr,
                                      const int* __restrict__ prow,
                                      const int* __restrict__ perm,
                                      const unsigned* __restrict__ st16p,
                                      const float* __restrict__ alphap,
                                      const float* __restrict__ dt) {
    int gid = blockIdx.x * blockDim.x + threadIdx.x;
    int i = gid >> 3;
    int q = gid & 7;
    if (i >= N_NODES) return;
    int j   = prow[i];
    int end = prow[i + 1];
    float a0 = 0, a1 = 0, a2 = 0, a3 = 0;
    for (; j + 4 <= end; j += 4) {
        unsigned e0 = __builtin_nontemporal_load(csr + j);
        unsigned e1 = __builtin_nontemporal_load(csr + j + 1);
        unsigned e2 = __builtin_nontemporal_load(csr + j + 2);
        unsigned e3 = __builtin_nontemporal_load(csr + j + 3);
        float w0 = (float)(e0 & 0x3fffu) * WDEQ;
        float w1 = (float)(e1 & 0x3fffu) * WDEQ;
        float w2 = (float)(e2 & 0x3fffu) * WDEQ;
        float w3 = (float)(e3 & 0x3fffu) * WDEQ;
        unsigned d0 = t8p[((e0 >> 14) << 3) + q];
        unsigned d1 = t8p[((e1 >> 14) << 3) + q];
        unsigned d2 = t8p[((e2 >> 14) << 3) + q];
        unsigned d3 = t8p[((e3 >> 14) << 3) + q];
        float f0, f1, f2, f3;
        UNPACK_FP8X4(d0, f0, f1, f2, f3);
        a0 = fmaf(w0, f0, a0); a1 = fmaf(w0, f1, a1);
        a2 = fmaf(w0, f2, a2); a3 = fmaf(w0, f3, a3);
        UNPACK_FP8X4(d1, f0, f1, f2, f3);
        a0 = fmaf(w1, f0, a0); a1 = fmaf(w1, f1, a1);
        a2 = fmaf(w1, f2, a2); a3 = fmaf(w1, f3, a3);
        UNPACK_FP8X4(d2, f0, f1, f2, f3);
        a0 = fmaf(w2, f0, a0); a1 = fmaf(w2, f1, a1);
        a2 = fmaf(w2, f2, a2); a3 = fmaf(w2, f3, a3);
        UNPACK_FP8X4(d3, f0, f1, f2, f3);
        a0 = fmaf(w3, f0, a0); a1 = fmaf(w3, f1, a1);
        a2 = fmaf(w3, f2, a2); a3 = fmaf(w3, f3, a3);
    }
    for (; j < end; ++j) {
        unsigned e0 = __builtin_nontemporal_load(csr + j);
        float w0 = (float)(e0 & 0x3fffu) * WDEQ;
        unsigned d0 = t8p[((e0 >> 14) << 3) + q];
        float f0, f1, f2, f3;
        UNPACK_FP8X4(d0, f0, f1, f2, f3);
        a0 = fmaf(w0, f0, a0); a1 = fmaf(w0, f1, a1);
        a2 = fmaf(w0, f2, a2); a3 = fmaf(w0, f3, a3);
    }
    float step = dt[0] * (1.0f / K_STEPS);
    float al = alphap[i];
    int d = perm[i];
    int fbase = d * DIM + (q << 2);
    float4 hv = *(const float4*)(h + fbase);
    uint2 sp = *(const uint2*)(st16p + (i << 4) + (q << 1));
    hv.x += step * (a0 - al * hv.x + bflo(sp.x));
    hv.y += step * (a1 - al * hv.y + bfhi(sp.x));
    hv.z += step * (a2 - al * hv.z + bflo(sp.y));
    hv.w += step * (a3 - al * hv.w + bfhi(sp.y));
    *(float4*)(h + fbase) = hv;
    h8p[(i << 3) + q] = pack_fp8x4(hv.x, hv.y, hv.z, hv.w);
}

extern "C" void kernel_launch(void* const* d_in, const int* in_sizes, int n_in,
                              void* d_out, int out_size, void* d_ws, size_t ws_size,
                              hipStream_t stream) {
    const float* xu          = (const float*)d_in[0];
    const float* xi          = (const float*)d_in[1];
    const float* su          = (const float*)d_in[2];
    const float* si          = (const float*)d_in[3];
    const float* ew          = (const float*)d_in[4];
    const float* alpha_logit = (const float*)d_in[5];
    const float* dt          = (const float*)d_in[6];
    const int*   es          = (const int*)d_in[7];
    const int*   ed          = (const int*)d_in[8];
    float* h = (float*)d_out;                     // fp32 h lives in d_out (node order)

    // ---- workspace layout (~34.3 MB peak) ----
    char* base = (char*)d_ws;
    unsigned int* norm_bits = (unsigned int*)base;              // 4 B
    int* cnt       = (int*)(base + 64);                         // 64 ints
    int* blockSums = (int*)(base + 512);                        // 256 ints
    int* sbh       = (int*)(base + 2048);                       // 160 ints
    const size_t SLOT = 640 * 1024;
    int*   deg     = (int*)(base + 4096 + 0 * SLOT);
    int*   perm    = (int*)(base + 4096 + 1 * SLOT);
    int*   pindex  = (int*)(base + 4096 + 2 * SLOT);
    int*   pdeg    = (int*)(base + 4096 + 3 * SLOT);
    int*   prow    = (int*)(base + 4096 + 4 * SLOT);            // N_NODES+1 entries
    int*   pcursor = (int*)(base + 4096 + 5 * SLOT);
    float* alphap  = (float*)(base + 4096 + 6 * SLOT);
    unsigned* csr  = (unsigned*)(base + 5u * 1024 * 1024);      // 9.6 MB
    // union region @15 MB: E1 (19.2 MB, dead after fill2) overlaps the mirrors
    char* region = base + 15u * 1024 * 1024;
    uint2*    E1    = (uint2*)region;                           // 19.2 MB
    unsigned* t8p   = (unsigned*)region;                        // 4.8 MB
    unsigned* h8p   = t8p + (size_t)N_NODES * 8;                // 4.8 MB
    unsigned* st16p = h8p + (size_t)N_NODES * 8;                // 9.6 MB

    hipMemsetAsync(norm_bits, 0, sizeof(unsigned int), stream);
    hipMemsetAsync(cnt, 0, 64 * sizeof(int), stream);
    hipMemsetAsync(sbh, 0, NSBP * sizeof(int), stream);
    hipMemsetAsync(deg, 0, (size_t)N_NODES * sizeof(int), stream);

    const int nodeb  = (N_NODES + 255) / 256;
    const int edgeb  = (N_EDGES + 255) / 256;
    const int node8b = (N_NODES * 8 + 255) / 256;
    const int chb    = (N_EDGES + CH - 1) / CH;   // 586

    norm_kernel<<<(N_NODES * 8 + 255) / 256, 256, 0, stream>>>(xu, xi, norm_bits);
    hist_kernel<<<edgeb, 256, 0, stream>>>(ed, deg);
    degcnt_kernel<<<nodeb, 256, 0, stream>>>(deg, cnt);
    scan_cnt_kernel<<<1, 64, 0, stream>>>(cnt);
    ticket_kernel<<<nodeb, 256, 0, stream>>>(deg, cnt, perm, pindex, pdeg, alphap, alpha_logit);
    scan_block_kernel<<<NB_SCAN, 256, 0, stream>>>(pdeg, prow, blockSums);
    scan_sums_kernel<<<1, 256, 0, stream>>>(blockSums);
    add_offsets_kernel<<<nodeb, 256, 0, stream>>>(prow, blockSums);
    pcopy_kernel<<<nodeb, 256, 0, stream>>>(prow, pcursor);
    // src-bucket coalesced sort -> E1 (src-banded edge stream)
    sbh_kernel<<<edgeb, 256, 0, stream>>>(es, pindex, sbh);
    sscan_kernel<<<1, 256, 0, stream>>>(sbh);
    sscatter_kernel<<<chb, 256, 0, stream>>>(es, ed, ew, pindex, sbh, E1);
    // CSR fill from src-sorted stream: rows become ~src-ascending
    fill2_kernel<<<edgeb, 256, 0, stream>>>(E1, pcursor, csr);
    // init AFTER fill2: mirrors overwrite E1's region
    init_kernel<<<node8b, 256, 0, stream>>>(xu, xi, su, si, norm_bits, pindex, h, h8p, st16p);

    for (int k = 0; k < K_STEPS; ++k) {
        gather1_kernel<<<node8b, 256, 0, stream>>>(h8p, t8p, csr, prow);
        gather2_update_kernel<<<node8b, 256, 0, stream>>>(t8p, h, h8p, csr, prow,
                                                          perm, st16p, alphap, dt);
    }
}

// Round 8
// 1055.541 us; speedup vs baseline: 1.3112x; 1.3112x over previous
//
#include <hip/hip_runtime.h>

#define N_USERS 100000
#define N_ITEMS 50000
#define N_NODES 150000
#define DIM     32
#define N_EDGES 2400000
#define K_STEPS 10

#define SCAN_CHUNK 1024
#define NB_SCAN ((N_NODES + SCAN_CHUNK - 1) / SCAN_CHUNK)   // 147 blocks
#define WDEQ 3.814697265625e-06f   // 2^-18

#define CH   4096      // edges per dscatter workgroup
#define NSB  147       // dst buckets: pdst >> 10
#define NSBP 160       // padded

typedef float v2f __attribute__((ext_vector_type(2)));

// ---------------- helpers: bf16 / fp8 ----------------
__device__ __forceinline__ float bflo(unsigned u) { return __uint_as_float(u << 16); }
__device__ __forceinline__ float bfhi(unsigned u) { return __uint_as_float(u & 0xffff0000u); }
__device__ __forceinline__ unsigned packbf(float a, float b) {   // RNE pack
    unsigned ua = __float_as_uint(a), ub = __float_as_uint(b);
    ua += 0x7fffu + ((ua >> 16) & 1u);
    ub += 0x7fffu + ((ub >> 16) & 1u);
    return (ua >> 16) | (ub & 0xffff0000u);
}
__device__ __forceinline__ unsigned pack_fp8x4(float a, float b, float c, float d) {
    unsigned r = 0;
    r = __builtin_amdgcn_cvt_pk_fp8_f32(a, b, r, false);   // bytes 0,1
    r = __builtin_amdgcn_cvt_pk_fp8_f32(c, d, r, true);    // bytes 2,3
    return r;
}
#define UNPACK_FP8X4(d, f0, f1, f2, f3)                          \
    { v2f _lo = __builtin_amdgcn_cvt_pk_f32_fp8((d), false);     \
      v2f _hi = __builtin_amdgcn_cvt_pk_f32_fp8((d), true);      \
      f0 = _lo[0]; f1 = _lo[1]; f2 = _hi[0]; f3 = _hi[1]; }

// ---------------- norm reduction: max over rows of sum(x^2) ----------------
__global__ void norm_kernel(const float* __restrict__ xu, const float* __restrict__ xi,
                            unsigned int* __restrict__ norm_bits) {
    int gid = blockIdx.x * blockDim.x + threadIdx.x;
    int row = gid >> 3;
    int q   = gid & 7;
    float s = 0.0f;
    if (row < N_NODES) {
        const float* x = (row < N_USERS) ? (xu + (size_t)row * DIM)
                                         : (xi + (size_t)(row - N_USERS) * DIM);
        float4 v = *(const float4*)(x + q * 4);
        s = v.x * v.x + v.y * v.y + v.z * v.z + v.w * v.w;
    }
    s += __shfl_xor(s, 1);
    s += __shfl_xor(s, 2);
    s += __shfl_xor(s, 4);
    s = fmaxf(s, __shfl_xor(s, 8));
    s = fmaxf(s, __shfl_xor(s, 16));
    s = fmaxf(s, __shfl_xor(s, 32));
    __shared__ float smax[4];
    int wave = threadIdx.x >> 6;
    if ((threadIdx.x & 63) == 0) smax[wave] = s;
    __syncthreads();
    if (threadIdx.x == 0) {
        float m = fmaxf(fmaxf(smax[0], smax[1]), fmaxf(smax[2], smax[3]));
        atomicMax(norm_bits, __float_as_uint(m));   // non-neg: uint order == float order
    }
}

// --------------------------- degree histogram ------------------------------
__global__ void hist_kernel(const int* __restrict__ ed, int* __restrict__ deg) {
    int e = blockIdx.x * blockDim.x + threadIdx.x;
    if (e >= N_EDGES) return;
    atomicAdd(&deg[ed[e]], 1);
}

// ----------------- degree-bucket counts (64 buckets) -----------------------
__global__ void degcnt_kernel(const int* __restrict__ deg, int* __restrict__ cnt) {
    __shared__ int lc[64];
    if (threadIdx.x < 64) lc[threadIdx.x] = 0;
    __syncthreads();
    int d = blockIdx.x * blockDim.x + threadIdx.x;
    if (d < N_NODES) {
        int dg = deg[d];
        atomicAdd(&lc[dg > 63 ? 63 : dg], 1);
    }
    __syncthreads();
    if (threadIdx.x < 64 && lc[threadIdx.x]) atomicAdd(&cnt[threadIdx.x], lc[threadIdx.x]);
}

// ------------- exclusive scan of the 64 bucket counts (1 wave) -------------
__global__ void scan_cnt_kernel(int* __restrict__ cnt) {
    int tid = threadIdx.x;          // 64 threads = 1 wave
    int v = cnt[tid];
    int inc = v;
    for (int off = 1; off < 64; off <<= 1) {
        int t = __shfl_up(inc, off);
        if (tid >= off) inc += t;
    }
    cnt[tid] = inc - v;             // exclusive offset; ticket advances it
}

// --- ticket: degree-sorted permutation. perm[pos]=node, pindex[node]=pos ---
__global__ void ticket_kernel(const int* __restrict__ deg, int* __restrict__ cnt,
                              int* __restrict__ perm, int* __restrict__ pindex,
                              int* __restrict__ pdeg, float* __restrict__ alphap,
                              const float* __restrict__ alpha_logit) {
    __shared__ int lcnt[64];
    __shared__ int lbase[64];
    int tid = threadIdx.x;
    if (tid < 64) lcnt[tid] = 0;
    __syncthreads();
    int d = blockIdx.x * blockDim.x + tid;
    int b = 0, rank = 0, dg = 0;
    if (d < N_NODES) {
        dg = deg[d];
        b = dg > 63 ? 63 : dg;
        rank = atomicAdd(&lcnt[b], 1);
    }
    __syncthreads();
    if (tid < 64 && lcnt[tid]) lbase[tid] = atomicAdd(&cnt[tid], lcnt[tid]);
    __syncthreads();
    if (d < N_NODES) {
        int pos = lbase[b] + rank;
        perm[pos] = d;
        pindex[d] = pos;
        pdeg[pos] = dg;
        alphap[pos] = 1.0f / (1.0f + __expf(-alpha_logit[d]));
    }
}

// ------------- per-block exclusive scan over pdeg (1024/block) -------------
__global__ void scan_block_kernel(const int* __restrict__ pdeg, int* __restrict__ excl,
                                  int* __restrict__ blockSums) {
    int base = blockIdx.x * SCAN_CHUNK + threadIdx.x * 4;
    int v0 = 0, v1 = 0, v2 = 0, v3 = 0;
    if (base + 3 < N_NODES) {
        int4 t = *(const int4*)(pdeg + base);
        v0 = t.x; v1 = t.y; v2 = t.z; v3 = t.w;
    } else {
        if (base + 0 < N_NODES) v0 = pdeg[base + 0];
        if (base + 1 < N_NODES) v1 = pdeg[base + 1];
        if (base + 2 < N_NODES) v2 = pdeg[base + 2];
    }
    int s = v0 + v1 + v2 + v3;
    int lane = threadIdx.x & 63;
    int inc = s;
    for (int off = 1; off < 64; off <<= 1) {
        int t = __shfl_up(inc, off);
        if (lane >= off) inc += t;
    }
    __shared__ int wsum[4];
    int wave = threadIdx.x >> 6;
    if (lane == 63) wsum[wave] = inc;
    __syncthreads();
    int woff = 0;
    for (int w = 0; w < 4; ++w) if (w < wave) woff += wsum[w];
    int excl_thread = woff + inc - s;
    if (base + 0 < N_NODES) excl[base + 0] = excl_thread;
    if (base + 1 < N_NODES) excl[base + 1] = excl_thread + v0;
    if (base + 2 < N_NODES) excl[base + 2] = excl_thread + v0 + v1;
    if (base + 3 < N_NODES) excl[base + 3] = excl_thread + v0 + v1 + v2;
    if (threadIdx.x == 255) blockSums[blockIdx.x] = woff + inc;
}

__global__ void scan_sums_kernel(int* __restrict__ blockSums) {
    __shared__ int buf[256];
    int tid = threadIdx.x;
    int v = (tid < NB_SCAN) ? blockSums[tid] : 0;
    buf[tid] = v;
    __syncthreads();
    for (int off = 1; off < 256; off <<= 1) {
        int t = (tid >= off) ? buf[tid - off] : 0;
        __syncthreads();
        buf[tid] += t;
        __syncthreads();
    }
    if (tid < NB_SCAN) blockSums[tid] = buf[tid] - v;   // exclusive
}

// prow[i] += blockoffset; sentinel prow[N_NODES] = N_EDGES
__global__ void add_offsets_kernel(int* __restrict__ prow, const int* __restrict__ blockSums) {
    int i = blockIdx.x * blockDim.x + threadIdx.x;
    if (i == 0) prow[N_NODES] = N_EDGES;
    if (i >= N_NODES) return;
    prow[i] += blockSums[i >> 10];
}

// sgb[b] = prow[b<<10]  (global cursor per dst bucket for dscatter)
__global__ void sgb_init_kernel(const int* __restrict__ prow, int* __restrict__ sgb) {
    int b = threadIdx.x;
    if (b < NSB) sgb[b] = prow[b << 10];
}

// --- LDS-staged coalesced scatter: edges -> E1, bucketed by pdst>>10 -------
// E1[k] = { csrword = pindex[src]<<14 | q14,  pdst }
__global__ __launch_bounds__(256) void dscatter_kernel(
        const int* __restrict__ es, const int* __restrict__ ed,
        const float* __restrict__ ew, const int* __restrict__ pindex,
        int* __restrict__ sgb, uint2* __restrict__ E1) {
    __shared__ int hist[NSBP];
    __shared__ int start[NSBP];
    __shared__ int lcur[NSBP];
    __shared__ int gbase[NSBP];
    __shared__ uint2 stage[CH];
    __shared__ unsigned char sbkt[CH];
    __shared__ int buf[256];
    int tid = threadIdx.x;
    int base0 = blockIdx.x * CH;
    int count = N_EDGES - base0;
    if (count > CH) count = CH;
    if (tid < NSBP) hist[tid] = 0;
    __syncthreads();
    // pass 1: local histogram over dst buckets
    for (int k = tid; k < count; k += 256)
        atomicAdd(&hist[(unsigned)pindex[ed[base0 + k]] >> 10], 1);
    __syncthreads();
    // exclusive scan of hist -> start, lcur
    int v = (tid < NSBP) ? hist[tid] : 0;
    buf[tid] = v;
    __syncthreads();
    for (int off = 1; off < 256; off <<= 1) {
        int t = (tid >= off) ? buf[tid - off] : 0;
        __syncthreads();
        buf[tid] += t;
        __syncthreads();
    }
    if (tid < NSBP) { start[tid] = buf[tid] - v; lcur[tid] = buf[tid] - v; }
    __syncthreads();
    // pass 2: stage payloads grouped by bucket
    for (int k = tid; k < count; k += 256) {
        int e = base0 + k;
        int pd = pindex[ed[e]];
        int b  = (unsigned)pd >> 10;
        float w = ew[e];
        unsigned q = (unsigned)(w * 262144.0f + 0.5f);   // w in [0,1/16): q < 16384
        if (q > 16383u) q = 16383u;
        uint2 p;
        p.x = ((unsigned)pindex[es[e]] << 14) | q;
        p.y = (unsigned)pd;
        int lp = atomicAdd(&lcur[b], 1);
        stage[lp] = p;
        sbkt[lp] = (unsigned char)b;     // b < 147 fits
    }
    __syncthreads();
    // pass 3: reserve global space per bucket
    if (tid < NSBP) gbase[tid] = hist[tid] ? atomicAdd(&sgb[tid], hist[tid]) : 0;
    __syncthreads();
    // pass 4: coalesced write-out
    for (int k = tid; k < count; k += 256) {
        int b = sbkt[k];
        E1[gbase[b] + (k - start[b])] = stage[k];
    }
}

// --- bucket fill: one block per dst bucket; ticket into exact row slots ----
// All csr writes land inside the bucket's ~64 KB window -> L2-absorbed.
__global__ __launch_bounds__(256) void bucket_fill_kernel(
        const uint2* __restrict__ E1, const int* __restrict__ prow,
        unsigned* __restrict__ csr) {
    __shared__ int lcur[1024];
    int b  = blockIdx.x;
    int r0 = b << 10;
    int r1 = r0 + 1024; if (r1 > N_NODES) r1 = N_NODES;
    int nr = r1 - r0;
    for (int r = threadIdx.x; r < nr; r += 256) lcur[r] = prow[r0 + r];
    __syncthreads();
    int base = prow[r0];
    int cnt  = prow[r1] - base;
    for (int k = threadIdx.x; k < cnt; k += 256) {
        uint2 p = E1[base + k];
        int pos = atomicAdd(&lcur[p.y - r0], 1);
        csr[pos] = p.x;
    }
}

// --- init: h(d_out) = x/norm; permuted fp8 mirror h8p; bf16 st16p ----------
__global__ void init_kernel(const float* __restrict__ xu, const float* __restrict__ xi,
                            const float* __restrict__ su, const float* __restrict__ si,
                            const unsigned int* __restrict__ norm_bits,
                            const int* __restrict__ pindex,
                            float* __restrict__ h, unsigned* __restrict__ h8p,
                            unsigned* __restrict__ st16p) {
    int gid = blockIdx.x * blockDim.x + threadIdx.x;
    int d = gid >> 3;
    int q = gid & 7;
    if (d >= N_NODES) return;
    float rn = rsqrtf(__uint_as_float(*norm_bits));
    int fbase = d * DIM + (q << 2);
    const float* x = (d < N_USERS) ? (xu + fbase) : (xi + fbase - N_USERS * DIM);
    const float* s = (d < N_USERS) ? (su + fbase) : (si + fbase - N_USERS * DIM);
    float4 v = *(const float4*)x;
    v.x *= rn; v.y *= rn; v.z *= rn; v.w *= rn;
    *(float4*)(h + fbase) = v;
    int i = pindex[d];
    h8p[(i << 3) + q] = pack_fp8x4(v.x, v.y, v.z, v.w);
    float4 sv = *(const float4*)s;
    uint2 sp;
    sp.x = packbf(sv.x * rn, sv.y * rn);
    sp.y = packbf(sv.z * rn, sv.w * rn);
    *(uint2*)(st16p + (i << 4) + (q << 1)) = sp;
}

// ---- hop-1 gather: t8p[i] = fp8( sum w * fp8row(h8p[psrc]) ) --------------
// 8 lanes/node, 1 dword (4 fp8) per lane per edge, unroll 4.
__global__ void gather1_kernel(const unsigned* __restrict__ h8p,
                               unsigned* __restrict__ t8p,
                               const unsigned* __restrict__ csr,
                               const int* __restrict__ prow) {
    int gid = blockIdx.x * blockDim.x + threadIdx.x;
    int i = gid >> 3;
    int q = gid & 7;
    if (i >= N_NODES) return;
    int j   = prow[i];
    int end = prow[i + 1];
    float a0 = 0, a1 = 0, a2 = 0, a3 = 0;
    for (; j + 4 <= end; j += 4) {
        unsigned e0 = __builtin_nontemporal_load(csr + j);
        unsigned e1 = __builtin_nontemporal_load(csr + j + 1);
        unsigned e2 = __builtin_nontemporal_load(csr + j + 2);
        unsigned e3 = __builtin_nontemporal_load(csr + j + 3);
        float w0 = (float)(e0 & 0x3fffu) * WDEQ;
        float w1 = (float)(e1 & 0x3fffu) * WDEQ;
        float w2 = (float)(e2 & 0x3fffu) * WDEQ;
        float w3 = (float)(e3 & 0x3fffu) * WDEQ;
        unsigned d0 = h8p[((e0 >> 14) << 3) + q];
        unsigned d1 = h8p[((e1 >> 14) << 3) + q];
        unsigned d2 = h8p[((e2 >> 14) << 3) + q];
        unsigned d3 = h8p[((e3 >> 14) << 3) + q];
        float f0, f1, f2, f3;
        UNPACK_FP8X4(d0, f0, f1, f2, f3);
        a0 = fmaf(w0, f0, a0); a1 = fmaf(w0, f1, a1);
        a2 = fmaf(w0, f2, a2); a3 = fmaf(w0, f3, a3);
        UNPACK_FP8X4(d1, f0, f1, f2, f3);
        a0 = fmaf(w1, f0, a0); a1 = fmaf(w1, f1, a1);
        a2 = fmaf(w1, f2, a2); a3 = fmaf(w1, f3, a3);
        UNPACK_FP8X4(d2, f0, f1, f2, f3);
        a0 = fmaf(w2, f0, a0); a1 = fmaf(w2, f1, a1);
        a2 = fmaf(w2, f2, a2); a3 = fmaf(w2, f3, a3);
        UNPACK_FP8X4(d3, f0, f1, f2, f3);
        a0 = fmaf(w3, f0, a0); a1 = fmaf(w3, f1, a1);
        a2 = fmaf(w3, f2, a2); a3 = fmaf(w3, f3, a3);
    }
    for (; j < end; ++j) {
        unsigned e0 = __builtin_nontemporal_load(csr + j);
        float w0 = (float)(e0 & 0x3fffu) * WDEQ;
        unsigned d0 = h8p[((e0 >> 14) << 3) + q];
        float f0, f1, f2, f3;
        UNPACK_FP8X4(d0, f0, f1, f2, f3);
        a0 = fmaf(w0, f0, a0); a1 = fmaf(w0, f1, a1);
        a2 = fmaf(w0, f2, a2); a3 = fmaf(w0, f3, a3);
    }
    t8p[(i << 3) + q] = pack_fp8x4(a0, a1, a2, a3);
}

// ---- hop-2 gather + update; h stays fp32 node-indexed in d_out ------------
__global__ void gather2_update_kernel(const unsigned* __restrict__ t8p,
                                      float* __restrict__ h,
                                      unsigned* __restrict__ h8p,
                                      const unsigned* __restrict__ csr,
                                      const int* __restrict__ prow,
                                      const int* __restrict__ perm,
                                      const unsigned* __restrict__ st16p,
                                      const float* __restrict__ alphap,
                                      const float* __restrict__ dt) {
    int gid = blockIdx.x * blockDim.x + threadIdx.x;
    int i = gid >> 3;
    int q = gid & 7;
    if (i >= N_NODES) return;
    int j   = prow[i];
    int end = prow[i + 1];
    float a0 = 0, a1 = 0, a2 = 0, a3 = 0;
    for (; j + 4 <= end; j += 4) {
        unsigned e0 = __builtin_nontemporal_load(csr + j);
        unsigned e1 = __builtin_nontemporal_load(csr + j + 1);
        unsigned e2 = __builtin_nontemporal_load(csr + j + 2);
        unsigned e3 = __builtin_nontemporal_load(csr + j + 3);
        float w0 = (float)(e0 & 0x3fffu) * WDEQ;
        float w1 = (float)(e1 & 0x3fffu) * WDEQ;
        float w2 = (float)(e2 & 0x3fffu) * WDEQ;
        float w3 = (float)(e3 & 0x3fffu) * WDEQ;
        unsigned d0 = t8p[((e0 >> 14) << 3) + q];
        unsigned d1 = t8p[((e1 >> 14) << 3) + q];
        unsigned d2 = t8p[((e2 >> 14) << 3) + q];
        unsigned d3 = t8p[((e3 >> 14) << 3) + q];
        float f0, f1, f2, f3;
        UNPACK_FP8X4(d0, f0, f1, f2, f3);
        a0 = fmaf(w0, f0, a0); a1 = fmaf(w0, f1, a1);
        a2 = fmaf(w0, f2, a2); a3 = fmaf(w0, f3, a3);
        UNPACK_FP8X4(d1, f0, f1, f2, f3);
        a0 = fmaf(w1, f0, a0); a1 = fmaf(w1, f1, a1);
        a2 = fmaf(w1, f2, a2); a3 = fmaf(w1, f3, a3);
        UNPACK_FP8X4(d2, f0, f1, f2, f3);
        a0 = fmaf(w2, f0, a0); a1 = fmaf(w2, f1, a1);
        a2 = fmaf(w2, f2, a2); a3 = fmaf(w2, f3, a3);
        UNPACK_FP8X4(d3, f0, f1, f2, f3);
        a0 = fmaf(w3, f0, a0); a1 = fmaf(w3, f1, a1);
        a2 = fmaf(w3, f2, a2); a3 = fmaf(w3, f3, a3);
    }
    for (; j < end; ++j) {
        unsigned e0 = __builtin_nontemporal_load(csr + j);
        float w0 = (float)(e0 & 0x3fffu) * WDEQ;
        unsigned d0 = t8p[((e0 >> 14) << 3) + q];
        float f0, f1, f2, f3;
        UNPACK_FP8X4(d0, f0, f1, f2, f3);
        a0 = fmaf(w0, f0, a0); a1 = fmaf(w0, f1, a1);
        a2 = fmaf(w0, f2, a2); a3 = fmaf(w0, f3, a3);
    }
    float step = dt[0] * (1.0f / K_STEPS);
    float al = alphap[i];
    int d = perm[i];
    int fbase = d * DIM + (q << 2);
    float4 hv = *(const float4*)(h + fbase);
    uint2 sp = *(const uint2*)(st16p + (i << 4) + (q << 1));
    hv.x += step * (a0 - al * hv.x + bflo(sp.x));
    hv.y += step * (a1 - al * hv.y + bfhi(sp.x));
    hv.z += step * (a2 - al * hv.z + bflo(sp.y));
    hv.w += step * (a3 - al * hv.w + bfhi(sp.y));
    *(float4*)(h + fbase) = hv;
    h8p[(i << 3) + q] = pack_fp8x4(hv.x, hv.y, hv.z, hv.w);
}

extern "C" void kernel_launch(void* const* d_in, const int* in_sizes, int n_in,
                              void* d_out, int out_size, void* d_ws, size_t ws_size,
                              hipStream_t stream) {
    const float* xu          = (const float*)d_in[0];
    const float* xi          = (const float*)d_in[1];
    const float* su          = (const float*)d_in[2];
    const float* si          = (const float*)d_in[3];
    const float* ew          = (const float*)d_in[4];
    const float* alpha_logit = (const float*)d_in[5];
    const float* dt          = (const float*)d_in[6];
    const int*   es          = (const int*)d_in[7];
    const int*   ed          = (const int*)d_in[8];
    float* h = (float*)d_out;                     // fp32 h lives in d_out (node order)

    // ---- workspace layout (~34.3 MB peak) ----
    char* base = (char*)d_ws;
    unsigned int* norm_bits = (unsigned int*)base;              // 4 B
    int* cnt       = (int*)(base + 64);                         // 64 ints
    int* blockSums = (int*)(base + 512);                        // 256 ints
    int* sgb       = (int*)(base + 2048);                       // 160 ints
    const size_t SLOT = 640 * 1024;
    int*   deg     = (int*)(base + 4096 + 0 * SLOT);
    int*   perm    = (int*)(base + 4096 + 1 * SLOT);
    int*   pindex  = (int*)(base + 4096 + 2 * SLOT);
    int*   pdeg    = (int*)(base + 4096 + 3 * SLOT);
    int*   prow    = (int*)(base + 4096 + 4 * SLOT);            // N_NODES+1 entries
    float* alphap  = (float*)(base + 4096 + 6 * SLOT);
    unsigned* csr  = (unsigned*)(base + 5u * 1024 * 1024);      // 9.6 MB
    // union region @15 MB: E1 (19.2 MB, dead after bucket_fill) overlaps mirrors
    char* region = base + 15u * 1024 * 1024;
    uint2*    E1    = (uint2*)region;                           // 19.2 MB
    unsigned* t8p   = (unsigned*)region;                        // 4.8 MB
    unsigned* h8p   = t8p + (size_t)N_NODES * 8;                // 4.8 MB
    unsigned* st16p = h8p + (size_t)N_NODES * 8;                // 9.6 MB

    hipMemsetAsync(norm_bits, 0, sizeof(unsigned int), stream);
    hipMemsetAsync(cnt, 0, 64 * sizeof(int), stream);
    hipMemsetAsync(deg, 0, (size_t)N_NODES * sizeof(int), stream);

    const int nodeb  = (N_NODES + 255) / 256;
    const int edgeb  = (N_EDGES + 255) / 256;
    const int node8b = (N_NODES * 8 + 255) / 256;
    const int chb    = (N_EDGES + CH - 1) / CH;   // 586

    norm_kernel<<<(N_NODES * 8 + 255) / 256, 256, 0, stream>>>(xu, xi, norm_bits);
    hist_kernel<<<edgeb, 256, 0, stream>>>(ed, deg);
    degcnt_kernel<<<nodeb, 256, 0, stream>>>(deg, cnt);
    scan_cnt_kernel<<<1, 64, 0, stream>>>(cnt);
    ticket_kernel<<<nodeb, 256, 0, stream>>>(deg, cnt, perm, pindex, pdeg, alphap, alpha_logit);
    scan_block_kernel<<<NB_SCAN, 256, 0, stream>>>(pdeg, prow, blockSums);
    scan_sums_kernel<<<1, 256, 0, stream>>>(blockSums);
    add_offsets_kernel<<<nodeb, 256, 0, stream>>>(prow, blockSums);
    sgb_init_kernel<<<1, 256, 0, stream>>>(prow, sgb);
    // dst-bucketed CSR build: coalesced scatter to E1, then L2-local ticket fill
    dscatter_kernel<<<chb, 256, 0, stream>>>(es, ed, ew, pindex, sgb, E1);
    bucket_fill_kernel<<<NSB, 256, 0, stream>>>(E1, prow, csr);
    // init AFTER bucket_fill: mirrors overwrite E1's region
    init_kernel<<<node8b, 256, 0, stream>>>(xu, xi, su, si, norm_bits, pindex, h, h8p, st16p);

    for (int k = 0; k < K_STEPS; ++k) {
        gather1_kernel<<<node8b, 256, 0, stream>>>(h8p, t8p, csr, prow);
        gather2_update_kernel<<<node8b, 256, 0, stream>>>(t8p, h, h8p, csr, prow,
                                                          perm, st16p, alphap, dt);
    }
}